// Round 13
// baseline (94.169 us; speedup 1.0000x reference)
//
#include <hip/hip_runtime.h>
#include <cstdint>
#include <cstddef>

// (B_, S, I, H) = (16, 2048, 256, 512)
#define BB 16
#define SS 2048
#define II 256
#define HH 512
#define MM (BB * SS)        /* 32768 GEMM rows        */
#define NNC 1024            /* out row width (re|im)  */
#define CHUNK 64
#define NCHUNK (SS / CHUNK) /* 32 chunks per batch    */
#define ALDW 40             /* padded Al row stride (bf16 elems) */

using bf16x8 = __attribute__((ext_vector_type(8))) short;
using short8 = __attribute__((ext_vector_type(8))) short;
using f32x4  = __attribute__((ext_vector_type(4))) float;

typedef __attribute__((address_space(3))) uint32_t       lds_u32;
typedef __attribute__((address_space(1))) const uint32_t glb_u32;

__device__ __forceinline__ short f2bf(float f) {
    uint32_t u = __float_as_uint(f);
    u += 0x7fffu + ((u >> 16) & 1u);   // RTNE
    return (short)(u >> 16);
}
__device__ __forceinline__ uint32_t packf16(float a, float b) {
    union { _Float16 h[2]; uint32_t u; } cv;
    cv.h[0] = (_Float16)a; cv.h[1] = (_Float16)b;
    return cv.u;
}
__device__ __forceinline__ float2 unpackf16(uint32_t u) {
    union { uint32_t u; _Float16 h[2]; } cv; cv.u = u;
    return make_float2((float)cv.h[0], (float)cv.h[1]);
}

// ---- B pack only (x conversion now fused into gemm): 128 blocks ----
__global__ __launch_bounds__(256) void cvt_b(const float* __restrict__ Bre,
                                             const float* __restrict__ Bim,
                                             short* __restrict__ Bc) {
    int idx = blockIdx.x * 256 + threadIdx.x;    // 32768
    int row = idx >> 5;                           // 0..1023
    int k0  = (idx & 31) << 3;                    // 0..248
    const float* src = ((row & 1) ? Bim : Bre) + (size_t)(row >> 1) * II + k0;
    float4 v0 = *(const float4*)src;
    float4 v1 = *(const float4*)(src + 4);
    short8 o;
    o[0]=f2bf(v0.x); o[1]=f2bf(v0.y); o[2]=f2bf(v0.z); o[3]=f2bf(v0.w);
    o[4]=f2bf(v1.x); o[5]=f2bf(v1.y); o[6]=f2bf(v1.z); o[7]=f2bf(v1.w);
    *(short8*)(Bc + (size_t)row * II + k0) = o;
}

// ---- GEMM: A reg-staged from x f32 (in-register f2bf), B via global_load_lds.
// Al padded to ALDW=40 elems/row (write conflicts broken; reads 2-way=free).
// Everything downstream of LDS (frag reads, MFMA, Y-write) r10/r12-VERBATIM.
__global__ __launch_bounds__(256, 3) void gemm_pack(const float* __restrict__ X,
                                                    const short* __restrict__ Bc,
                                                    uint32_t* __restrict__ Y) {
    __shared__ short Al[2][128 * ALDW];
    __shared__ short Bl[2][128 * 32];

    const int xcd = blockIdx.x & 7;
    const int k   = blockIdx.x >> 3;          // 0..255
    const int mt  = xcd * 32 + (k >> 3);      // 0..255 (bijective; r9-verified)
    const int nt  = k & 7;
    const int m0 = mt * 128, n0 = nt * 128;
    const int t  = threadIdx.x;
    const int w  = t >> 6, l = t & 63;
    const int fr = l & 15, fg = l >> 4;
    const int wr = w >> 1, wc = w & 1;

    // A staging geometry: thread t -> row = t>>1, khalf = t&1 (16 f32 = 64 B)
    const int arow = t >> 1, akh = t & 1;
    const float* xrow = X + (size_t)(m0 + arow) * II + akh * 16;
    short* aldst = &Al[0][arow * ALDW + akh * 16];   // [0] buffer; [1] = +128*ALDW

    f32x4 acc[4][4] = {};

    // ---------------- prologue: stage k-step 0 ----------------
    {
        float4 v0 = *(const float4*)(xrow + 0);
        float4 v1 = *(const float4*)(xrow + 4);
        float4 v2 = *(const float4*)(xrow + 8);
        float4 v3 = *(const float4*)(xrow + 12);
        short8 o0, o1;
        o0[0]=f2bf(v0.x); o0[1]=f2bf(v0.y); o0[2]=f2bf(v0.z); o0[3]=f2bf(v0.w);
        o0[4]=f2bf(v1.x); o0[5]=f2bf(v1.y); o0[6]=f2bf(v1.z); o0[7]=f2bf(v1.w);
        o1[0]=f2bf(v2.x); o1[1]=f2bf(v2.y); o1[2]=f2bf(v2.z); o1[3]=f2bf(v2.w);
        o1[4]=f2bf(v3.x); o1[5]=f2bf(v3.y); o1[6]=f2bf(v3.z); o1[7]=f2bf(v3.w);
        *(short8*)(aldst + 0) = o0;
        *(short8*)(aldst + 8) = o1;
    }
#pragma unroll
    for (int i = 0; i < 2; ++i) {
        const int ch = i * 256 + t;
        __builtin_amdgcn_global_load_lds(
            (glb_u32*)(Bc + (size_t)(n0 + (ch >> 2)) * II + ((ch & 3) << 3)),
            (lds_u32*)&Bl[0][ch * 8], 16, 0, 0);
    }
    __syncthreads();

    // ---------------- main loop ----------------
    for (int ks = 0; ks < 8; ++ks) {         // K = 8 * 32
        const int cur = ks & 1, nxt = cur ^ 1;
        float4 v0, v1, v2, v3;
        if (ks < 7) {
            // issue next A loads early (latency hides under MFMA below)
            const float* xs = xrow + (ks + 1) * 32;
            v0 = *(const float4*)(xs + 0);
            v1 = *(const float4*)(xs + 4);
            v2 = *(const float4*)(xs + 8);
            v3 = *(const float4*)(xs + 12);
#pragma unroll
            for (int i = 0; i < 2; ++i) {
                const int ch = i * 256 + t;
                __builtin_amdgcn_global_load_lds(
                    (glb_u32*)(Bc + (size_t)(n0 + (ch >> 2)) * II + (ks + 1) * 32 + ((ch & 3) << 3)),
                    (lds_u32*)&Bl[nxt][ch * 8], 16, 0, 0);
            }
        }
        bf16x8 a[4], b[4];
#pragma unroll
        for (int mi = 0; mi < 4; ++mi)
            a[mi] = *(const bf16x8*)&Al[cur][(wr * 64 + mi * 16 + fr) * ALDW + fg * 8];
#pragma unroll
        for (int ni = 0; ni < 4; ++ni)
            b[ni] = *(const bf16x8*)&Bl[cur][(wc * 64 + ni * 16 + fr) * 32 + fg * 8];
#pragma unroll
        for (int mi = 0; mi < 4; ++mi)
#pragma unroll
            for (int ni = 0; ni < 4; ++ni)
                acc[mi][ni] = __builtin_amdgcn_mfma_f32_16x16x32_bf16(
                    a[mi], b[ni], acc[mi][ni], 0, 0, 0);
        if (ks < 7) {
            short8 o0, o1;
            o0[0]=f2bf(v0.x); o0[1]=f2bf(v0.y); o0[2]=f2bf(v0.z); o0[3]=f2bf(v0.w);
            o0[4]=f2bf(v1.x); o0[5]=f2bf(v1.y); o0[6]=f2bf(v1.z); o0[7]=f2bf(v1.w);
            o1[0]=f2bf(v2.x); o1[1]=f2bf(v2.y); o1[2]=f2bf(v2.z); o1[3]=f2bf(v2.w);
            o1[4]=f2bf(v3.x); o1[5]=f2bf(v3.y); o1[6]=f2bf(v3.z); o1[7]=f2bf(v3.w);
            short* ad = aldst + nxt * 128 * ALDW;
            *(short8*)(ad + 0) = o0;
            *(short8*)(ad + 8) = o1;
        }
        __syncthreads();
    }

    // ---------------- Y write: r10/r12 VERBATIM ----------------
#pragma unroll
    for (int mi = 0; mi < 4; ++mi)
#pragma unroll
        for (int ni = 0; ni < 4; ++ni) {
            const int row0 = m0 + wr * 64 + mi * 16 + fg * 4;
            const int ncol = n0 + wc * 64 + ni * 16 + fr;
#pragma unroll
            for (int r = 0; r < 4; ++r) {
                float v = acc[mi][ni][r];
                float o = __shfl_xor(v, 1);
                if (!(fr & 1))
                    Y[(size_t)(row0 + r) * HH + (ncol >> 1)] = packf16(v, o);
            }
        }
}

// ---- local chunk scan (h0=0) over packed Y -> chunk-end state E (r12 VERBATIM) ----
__global__ __launch_bounds__(512) void scan_e(const uint32_t* __restrict__ Y,
                                              const float* __restrict__ nu,
                                              const float* __restrict__ th,
                                              float2* __restrict__ E) {
    const int g = blockIdx.x;                 // 512 = 16 b * 32 c
    const int b = g >> 5, c = g & 31;
    const int h = threadIdx.x;
    const float env = __expf(nu[h]);
    const float rad = __expf(-env);
    float s, cs; __sincosf(th[h], &s, &cs);
    const float lre = rad * cs, lim = rad * s;
    const uint32_t* base = Y + ((size_t)b * SS + (size_t)c * CHUNK) * HH + h;
    float hre = 0.f, him = 0.f;
#pragma unroll 8
    for (int t = 0; t < CHUNK; ++t) {
        float2 y = unpackf16(base[(size_t)t * HH]);
        const float nr = lre * hre - lim * him + y.x;
        him = lre * him + lim * hre + y.y;
        hre = nr;
    }
    E[(size_t)g * HH + h] = make_float2(hre, him);
}

// ---- final scan: inline carry from E + r12 scan body (VERBATIM) ----
__global__ __launch_bounds__(512) void scan_final(const uint32_t* __restrict__ Y,
                                                  const float2* __restrict__ E,
                                                  const float* __restrict__ nu,
                                                  const float* __restrict__ th,
                                                  float* __restrict__ out) {
    const int g = blockIdx.x;                 // 512 = 16 b * 32 c
    const int b = g >> 5, c = g & 31;
    const int h = threadIdx.x;
    const float env = __expf(nu[h]);
    const float rad = __expf(-env);
    float s, cs; __sincosf(th[h], &s, &cs);
    const float lre = rad * cs, lim = rad * s;

    const float rL = __expf(-(float)CHUNK * env);
    float sL, cL; __sincosf((float)CHUNK * th[h], &sL, &cL);
    const float l64re = rL * cL, l64im = rL * sL;
    float pre = 0.f, pim = 0.f;
    for (int j = 0; j < c; ++j) {
        const float2 e = E[((size_t)(b * NCHUNK + j)) * HH + h];
        const float nr = l64re * pre - l64im * pim + e.x;
        pim = l64re * pim + l64im * pre + e.y;
        pre = nr;
    }

    float hre = pre, him = pim;
    const uint32_t* yb = Y + ((size_t)b * SS + (size_t)c * CHUNK) * HH + h;
    float* ob = out + ((size_t)b * SS + (size_t)c * CHUNK) * NNC;
#pragma unroll 4
    for (int t = 0; t < CHUNK; ++t) {
        float2 y = unpackf16(yb[(size_t)t * HH]);
        const float nr = lre * hre - lim * him + y.x;
        him = lre * him + lim * hre + y.y;
        hre = nr;
        ob[(size_t)t * NNC + h]      = hre;
        ob[(size_t)t * NNC + HH + h] = him;
    }
}

extern "C" void kernel_launch(void* const* d_in, const int* in_sizes, int n_in,
                              void* d_out, int out_size, void* d_ws, size_t ws_size,
                              hipStream_t stream) {
    const float* x   = (const float*)d_in[0];
    const float* nu  = (const float*)d_in[1];
    const float* th  = (const float*)d_in[2];
    const float* Bre = (const float*)d_in[3];
    const float* Bim = (const float*)d_in[4];
    float* out = (float*)d_out;

    // ws: Bc bf16 512 KiB | Y u32 64 MiB | E 2 MiB
    char* ws = (char*)d_ws;
    short*    Bc = (short*)ws;
    uint32_t* Y  = (uint32_t*)(ws + (size_t)NNC * II * 2);
    float2*   E  = (float2*)((char*)Y + (size_t)MM * HH * 4);

    cvt_b<<<(NNC * II / 8) / 256, 256, 0, stream>>>(Bre, Bim, Bc);
    gemm_pack<<<(MM / 128) * (NNC / 128), 256, 0, stream>>>(x, Bc, Y);
    scan_e<<<BB * NCHUNK, HH, 0, stream>>>(Y, nu, th, E);
    scan_final<<<BB * NCHUNK, HH, 0, stream>>>(Y, E, nu, th, out);
}